// Round 7
// baseline (63.547 us; speedup 1.0000x reference)
//
#include <hip/hip_runtime.h>
#include <math.h>

#define NN 128
#define FF 32
#define DCAP 64   // max-degree capacity (actual max ~45 for seed-0 graph)

__device__ __forceinline__ float sig_(float v) { return 1.f / (1.f + expf(-v)); }

// d[0..15] <- s[0..15] via 4x float4 (global: 2 unique 64B segs/wave -> broadcast)
__device__ __forceinline__ void ld16(float* __restrict__ d, const float* s) {
    const float4* p = (const float4*)s;
    const float4 a = p[0], b = p[1], c = p[2], e4 = p[3];
    d[0]=a.x;  d[1]=a.y;  d[2]=a.z;  d[3]=a.w;
    d[4]=b.x;  d[5]=b.y;  d[6]=b.z;  d[7]=b.w;
    d[8]=c.x;  d[9]=c.y;  d[10]=c.z; d[11]=c.w;
    d[12]=e4.x; d[13]=e4.y; d[14]=e4.z; d[15]=e4.w;
}

__device__ __forceinline__ float dot16(const float4 a, const float4 b,
                                       const float4 c, const float4 d,
                                       const float* __restrict__ w) {
    float s = a.x*w[0] + a.y*w[1] + a.z*w[2] + a.w*w[3];
    s += b.x*w[4] + b.y*w[5] + b.z*w[6] + b.w*w[7];
    s += c.x*w[8] + c.y*w[9] + c.z*w[10] + c.w*w[11];
    s += d.x*w[12] + d.y*w[13] + d.z*w[14] + d.w*w[15];
    return s;
}

// ---------------------------------------------------------------------------
// Zero the 8 accumulators (sin1..4, rout1..4): 8*4096 floats contiguous.
// ---------------------------------------------------------------------------
__global__ void k_zero(float* __restrict__ z) {
    z[blockIdx.x * 256 + threadIdx.x] = 0.f;
}

// ---------------------------------------------------------------------------
// Step 0 (messages == 0). One wave per directed edge e=(i,j):
//   wux = Wu[e]@x_i, wcmx = Wcm[e]@x_i (persisted); M1 = sig(wux+bu)*tanh(wcmx+bcm)
//   sin1[j] += M1;  lookahead r1 = sig(wux + Uu[e]@M1 + bu); RM = r1*M1;
//   rout1[i] += RM.
// Lane l: f = l>>1 (output row), h = l&1 (16-col half window w0 = 16h).
// ---------------------------------------------------------------------------
__global__ __launch_bounds__(256) void k_step0(
        const int* __restrict__ adj, const float* __restrict__ x,
        const float* __restrict__ Wu, const float* __restrict__ Wcm,
        const float* __restrict__ Uu,
        const float* __restrict__ bu, const float* __restrict__ bcm,
        float* __restrict__ WUX, float* __restrict__ WCMX,
        float* __restrict__ M1, float* __restrict__ RM,
        float* __restrict__ sin1, float* __restrict__ rout1) {
    __shared__ float lm[4][FF], lrm[4][FF];
    const int wv = threadIdx.x >> 6;
    const int e = blockIdx.x * 4 + wv;
    if (!adj[e]) return;
    const int l = threadIdx.x & 63;
    const int i = e >> 7, j = e & 127;
    const int f = l >> 1, h = l & 1, ll = l & 31;
    const int w0 = h * 16;
    const size_t rb = ((size_t)e * FF + f) * FF + w0;

    float xw[16];
    ld16(xw, x + i * FF + w0);
    const float4* wp = (const float4*)(Wu + rb);
    float a0 = dot16(wp[0], wp[1], wp[2], wp[3], xw);
    a0 += __shfl_xor(a0, 1);
    const float4* cp = (const float4*)(Wcm + rb);
    float a1 = dot16(cp[0], cp[1], cp[2], cp[3], xw);
    a1 += __shfl_xor(a1, 1);
    const float bu_f = bu[f];
    if (h == 0) {
        WUX[(size_t)e * FF + f] = a0;
        WCMX[(size_t)e * FF + f] = a1;
    }
    const float mn = sig_(a0 + bu_f) * tanhf(a1 + bcm[f]);
    if (h == 0) lm[wv][f] = mn;
    float vw[16];
    ld16(vw, &lm[wv][w0]);     // intra-wave LDS recirculation (in-order pipe)
    const float4* up = (const float4*)(Uu + rb);
    float aR = dot16(up[0], up[1], up[2], up[3], vw);
    aR += __shfl_xor(aR, 1);
    const float rp = sig_(a0 + aR + bu_f);
    if (h == 0) lrm[wv][f] = rp * mn;
    if (l < 32) {
        const float mvv = lm[wv][ll];
        M1[(size_t)e * FF + ll] = mvv;
        atomicAdd(&sin1[j * FF + ll], mvv);
        const float rmv = lrm[wv][ll];
        RM[(size_t)e * FF + ll] = rmv;
        atomicAdd(&rout1[i * FF + ll], rmv);
    }
}

// ---------------------------------------------------------------------------
// Steps 1..3. One wave per edge e=(i,j):
//   prev = sin_t[i] - M_in[j,i]      (direct broadcast loads, no shuffles)
//   z = sig(WUX + Uu[e]@prev + bu)   (Uu row register-cached, reused for r')
//   rs = rout_t[i] - RM[e];  cm = tanh(WCMX + Ucm[e]@rs + bcm)
//   mnew = (1-z)*prev + z*cm -> M_out, sin_next[j] +=
//   r' = sig(WUX + Uu[e]@mnew + bu); RM[e] = r'*mnew; rout_next[i] +=
// ---------------------------------------------------------------------------
__global__ __launch_bounds__(256) void k_step(
        const int* __restrict__ adj,
        const float* __restrict__ Uu, const float* __restrict__ Ucm,
        const float* __restrict__ bu, const float* __restrict__ bcm,
        const float* __restrict__ WUX, const float* __restrict__ WCMX,
        const float* __restrict__ M_in, float* __restrict__ M_out,
        float* __restrict__ RM,
        const float* __restrict__ sin_t, const float* __restrict__ rout_t,
        float* __restrict__ sin_next, float* __restrict__ rout_next) {
    __shared__ float lm[4][FF], lrm[4][FF];
    const int wv = threadIdx.x >> 6;
    const int e = blockIdx.x * 4 + wv;
    if (!adj[e]) return;
    const int l = threadIdx.x & 63;
    const int i = e >> 7, j = e & 127;
    const int f = l >> 1, h = l & 1, ll = l & 31;
    const int w0 = h * 16;
    const size_t rb = ((size_t)e * FF + f) * FF + w0;

    const float4* up = (const float4*)(Uu + rb);
    const float4 u0 = up[0], u1 = up[1], u2 = up[2], u3 = up[3];

    float sw[16], mw[16], vw[16];
    ld16(sw, sin_t + i * FF + w0);
    ld16(mw, M_in + ((size_t)j * NN + i) * FF + w0);
#pragma unroll
    for (int k = 0; k < 16; ++k) vw[k] = sw[k] - mw[k];
    float aP = dot16(u0, u1, u2, u3, vw);
    aP += __shfl_xor(aP, 1);
    const float bu_f  = bu[f];
    const float wux_f = WUX[(size_t)e * FF + f];
    const float z = sig_(wux_f + aP + bu_f);

    ld16(sw, rout_t + i * FF + w0);
    ld16(mw, RM + (size_t)e * FF + w0);
#pragma unroll
    for (int k = 0; k < 16; ++k) vw[k] = sw[k] - mw[k];
    const float4* cp = (const float4*)(Ucm + rb);
    float aC = dot16(cp[0], cp[1], cp[2], cp[3], vw);
    aC += __shfl_xor(aC, 1);
    const float cmv = tanhf(WCMX[(size_t)e * FF + f] + aC + bcm[f]);

    const float prev_f = sin_t[i * FF + f] - M_in[((size_t)j * NN + i) * FF + f];
    const float mn = (1.f - z) * prev_f + z * cmv;
    if (h == 0) lm[wv][f] = mn;
    ld16(vw, &lm[wv][w0]);
    float aR = dot16(u0, u1, u2, u3, vw);
    aR += __shfl_xor(aR, 1);
    const float rp = sig_(wux_f + aR + bu_f);
    if (h == 0) lrm[wv][f] = rp * mn;
    if (l < 32) {
        const float mvv = lm[wv][ll];
        M_out[(size_t)e * FF + ll] = mvv;
        atomicAdd(&sin_next[j * FF + ll], mvv);
        const float rmv = lrm[wv][ll];
        RM[(size_t)e * FF + ll] = rmv;
        atomicAdd(&rout_next[i * FF + ll], rmv);
    }
}

// ---------------------------------------------------------------------------
// Step 4 + final encode fused, node-block (512 thr = 8 waves, block = node i).
// outsum is block-local (sum of node i's new out-messages) -> no atomics, no
// separate k_final dispatch. No r-lookahead needed in the last step.
// ---------------------------------------------------------------------------
__global__ __launch_bounds__(512) void k_last(
        const int* __restrict__ adj, const float* __restrict__ x,
        const float* __restrict__ Uu, const float* __restrict__ Ucm,
        const float* __restrict__ bu, const float* __restrict__ bcm,
        const float* __restrict__ WUX, const float* __restrict__ WCMX,
        const float* __restrict__ M_in, const float* __restrict__ RM,
        const float* __restrict__ sin4, const float* __restrict__ rout4,
        const float* __restrict__ Unf, const float* __restrict__ Unm,
        float* __restrict__ out) {
    const int i = blockIdx.x;
    const int t = threadIdx.x;
    const int wv = t >> 6, l = t & 63;
    const int f = l >> 1, h = l & 1;
    const int w0 = h * 16;

    __shared__ int nbr[DCAP];
    __shared__ int wcnt[2];
    __shared__ float sin_s[FF], rout_s[FF], xs[FF], os_s[FF];
    __shared__ float opp[8][FF];

    const bool pred = (t < NN) && (adj[i * NN + t] != 0);
    const unsigned long long mask = __ballot(pred);
    if (wv < 2 && l == 0) wcnt[wv] = __popcll(mask);
    if (t < FF) {
        sin_s[t]  = sin4[i * FF + t];
        rout_s[t] = rout4[i * FF + t];
        xs[t]     = x[i * FF + t];
    }
    __syncthreads();
    if (pred) {
        const int base = (wv == 1) ? wcnt[0] : 0;
        nbr[base + __popcll(mask & ((1ull << (unsigned)l) - 1ull))] = t;
    }
    __syncthreads();
    const int dg = wcnt[0] + wcnt[1];

    float osf = 0.f;
    for (int s = wv; s < dg; s += 8) {
        const int j = nbr[s];
        const size_t e = (size_t)i * NN + j;
        const size_t rb = (e * FF + f) * FF + w0;
        float sw[16], mw[16], vw[16];
        ld16(sw, &sin_s[w0]);
        ld16(mw, M_in + ((size_t)j * NN + i) * FF + w0);
#pragma unroll
        for (int k = 0; k < 16; ++k) vw[k] = sw[k] - mw[k];
        const float4* up = (const float4*)(Uu + rb);
        float aP = dot16(up[0], up[1], up[2], up[3], vw);
        aP += __shfl_xor(aP, 1);
        const float z = sig_(WUX[e * FF + f] + aP + bu[f]);

        ld16(sw, &rout_s[w0]);
        ld16(mw, RM + e * FF + w0);
#pragma unroll
        for (int k = 0; k < 16; ++k) vw[k] = sw[k] - mw[k];
        const float4* cp = (const float4*)(Ucm + rb);
        float aC = dot16(cp[0], cp[1], cp[2], cp[3], vw);
        aC += __shfl_xor(aC, 1);
        const float cmv = tanhf(WCMX[e * FF + f] + aC + bcm[f]);

        const float prev_f = sin_s[f] - M_in[((size_t)j * NN + i) * FF + f];
        osf += (1.f - z) * prev_f + z * cmv;
    }
    if (h == 0) opp[wv][f] = osf;
    __syncthreads();
    if (t < FF) {
        float s = 0.f;
#pragma unroll
        for (int g = 0; g < 8; ++g) s += opp[g][t];
        os_s[t] = s;
    }
    __syncthreads();
    if (t < 64) {
        const size_t rb = ((size_t)i * FF + f) * FF + w0;
        float xw[16], ow[16];
        ld16(xw, &xs[w0]);
        ld16(ow, &os_s[w0]);
        const float4* fp = (const float4*)(Unf + rb);
        const float4* mp = (const float4*)(Unm + rb);
        float a = dot16(fp[0], fp[1], fp[2], fp[3], xw)
                + dot16(mp[0], mp[1], mp[2], mp[3], ow);
        a += __shfl_xor(a, 1);
        if (h == 0) out[i * FF + f] = fmaxf(a, 0.f);
    }
}

extern "C" void kernel_launch(void* const* d_in, const int* in_sizes, int n_in,
                              void* d_out, int out_size, void* d_ws, size_t ws_size,
                              hipStream_t stream) {
    const float* x   = (const float*)d_in[0];
    const int*   adj = (const int*)d_in[1];
    const float* Wu  = (const float*)d_in[2];
    const float* Uu  = (const float*)d_in[3];
    const float* Wcm = (const float*)d_in[4];
    const float* Ucm = (const float*)d_in[5];
    const float* bu  = (const float*)d_in[6];
    const float* bcm = (const float*)d_in[7];
    const float* Unf = (const float*)d_in[8];
    const float* Unm = (const float*)d_in[9];
    float* out = (float*)d_out;

    const size_t EF = (size_t)NN * NN * FF;  // 524288 floats per dense [N,N,F]
    const size_t NF = (size_t)NN * FF;       // 4096
    float* p    = (float*)d_ws;
    float* MA   = p; p += EF;
    float* MB   = p; p += EF;
    float* WUX  = p; p += EF;
    float* WCMX = p; p += EF;
    float* RM   = p; p += EF;
    float* acc  = p; p += 8 * NF;            // sin1..4, rout1..4 (contiguous)
    float* sinb[4]  = {acc, acc + NF, acc + 2 * NF, acc + 3 * NF};
    float* routb[4] = {acc + 4 * NF, acc + 5 * NF, acc + 6 * NF, acc + 7 * NF};
    // ws use: 10 MiB + 128 KiB

    const int EG = (NN * NN) / 4;  // 4096 blocks, 4 edge-waves each

    k_zero<<<(8 * NF) / 256, 256, 0, stream>>>(acc);
    k_step0<<<EG, 256, 0, stream>>>(adj, x, Wu, Wcm, Uu, bu, bcm,
                                    WUX, WCMX, MA, RM, sinb[0], routb[0]);
    // t=1: MA->MB ; t=2: MB->MA ; t=3: MA->MB ; t=4 (k_last): reads MB
    k_step<<<EG, 256, 0, stream>>>(adj, Uu, Ucm, bu, bcm, WUX, WCMX,
                                   MA, MB, RM, sinb[0], routb[0],
                                   sinb[1], routb[1]);
    k_step<<<EG, 256, 0, stream>>>(adj, Uu, Ucm, bu, bcm, WUX, WCMX,
                                   MB, MA, RM, sinb[1], routb[1],
                                   sinb[2], routb[2]);
    k_step<<<EG, 256, 0, stream>>>(adj, Uu, Ucm, bu, bcm, WUX, WCMX,
                                   MA, MB, RM, sinb[2], routb[2],
                                   sinb[3], routb[3]);
    k_last<<<NN, 512, 0, stream>>>(adj, x, Uu, Ucm, bu, bcm, WUX, WCMX,
                                   MB, RM, sinb[3], routb[3], Unf, Unm, out);
}

// Round 8
// 50.135 us; speedup vs baseline: 1.2675x; 1.2675x over previous
//
#include <hip/hip_runtime.h>
#include <math.h>

#define NN 128
#define FF 32
#define NBLK_E 896            // 3584 wave slots for step kernels (grid-stride)
#define GSTRIDE (NBLK_E * 4)

__device__ __forceinline__ float sig_(float v) { return 1.f / (1.f + expf(-v)); }

// acc += u4 . vec[g0..g0+3]  (vec in vector layout: lane v holds vec[v&31])
#define DOT4(acc, u4, vec, g0)                                         \
    acc += u4.x * __shfl(vec, (g0) + 0) + u4.y * __shfl(vec, (g0) + 1) \
         + u4.z * __shfl(vec, (g0) + 2) + u4.w * __shfl(vec, (g0) + 3);

// ---------------------------------------------------------------------------
// Prep (1 block, 1024 thr): zero the 8 accumulators (sin1..4, rout1..4) and
// build a globally compacted edge list in ascending e order (deterministic)
// plus per-row offsets. Thread t owns adjacency cells [t*16, t*16+16) (always
// within one row since 128 cells/row). Ballot-free flag scan + shfl prefix.
// meta[0] = E; meta[1+i] = row_start[i] (i=0..128).
// ---------------------------------------------------------------------------
__global__ __launch_bounds__(1024) void k_prep(
        const int* __restrict__ adj, float* __restrict__ acc,
        int* __restrict__ elist, int* __restrict__ meta) {
    const int t = threadIdx.x, lane = t & 63, wid = t >> 6;
    for (int g = t; g < 8 * NN * FF; g += 1024) acc[g] = 0.f;

    const int4* ap = (const int4*)(adj + t * 16);
    const int4 v0 = ap[0], v1 = ap[1], v2 = ap[2], v3 = ap[3];
    const int c[16] = {v0.x, v0.y, v0.z, v0.w, v1.x, v1.y, v1.z, v1.w,
                       v2.x, v2.y, v2.z, v2.w, v3.x, v3.y, v3.z, v3.w};
    int fl = 0;
#pragma unroll
    for (int k = 0; k < 16; ++k)
        if (c[k]) fl |= (1 << k);
    const int cnt = __popc(fl);

    int inc = cnt;                       // inclusive scan within wave
#pragma unroll
    for (int d = 1; d < 64; d <<= 1) {
        const int n = __shfl_up(inc, d);
        if (lane >= d) inc += n;
    }
    __shared__ int wtot[16], wbase[16], Etot_s;
    if (lane == 63) wtot[wid] = inc;
    __syncthreads();
    if (t < 16) {                        // scan the 16 wave totals
        const int v = wtot[t];
        int pz = v;
#pragma unroll
        for (int d = 1; d < 16; d <<= 1) {
            const int n = __shfl_up(pz, d);
            if (t >= d) pz += n;
        }
        wbase[t] = pz - v;
        if (t == 15) Etot_s = pz;
    }
    __syncthreads();
    const int base = wbase[wid] + (inc - cnt);
    if ((t & 7) == 0) meta[1 + (t >> 3)] = base;   // row_start[t/8]
    if (t == 0) { meta[0] = Etot_s; meta[129] = Etot_s; }
    int off = base;
#pragma unroll
    for (int k = 0; k < 16; ++k)
        if ((fl >> k) & 1) elist[off++] = t * 16 + k;
}

// ---------------------------------------------------------------------------
// Step 0 (messages == 0). One wave per edge (grid-stride over compact list):
//   wux = Wu[e]@x_i, wcmx = Wcm[e]@x_i (persisted); M1 = sig(wux+bu)*tanh(wcmx+bcm)
//   sin1[j] += M1; lookahead r1 = sig(wux + Uu[e]@M1 + bu); RM = r1*M1;
//   rout1[i] += RM.
// Lane l: f = l>>1 (output row), h = l&1 (16-col half); ll = l&31 (vector).
// ---------------------------------------------------------------------------
__global__ __launch_bounds__(256) void k_step0(
        const int* __restrict__ elist, const int* __restrict__ meta,
        const float* __restrict__ x,
        const float* __restrict__ Wu, const float* __restrict__ Wcm,
        const float* __restrict__ Uu,
        const float* __restrict__ bu, const float* __restrict__ bcm,
        float* __restrict__ WUX, float* __restrict__ WCMX,
        float* __restrict__ M1, float* __restrict__ RM,
        float* __restrict__ sin1, float* __restrict__ rout1) {
    const int E = meta[0];
    const int gw = blockIdx.x * 4 + (threadIdx.x >> 6);
    const int l = threadIdx.x & 63;
    const int f = l >> 1, h = l & 1, ll = l & 31;
    const float bu_f = bu[f], bcm_f = bcm[f];
    for (int slot = gw; slot < E; slot += GSTRIDE) {
        const int e = elist[slot];
        const int i = e >> 7, j = e & 127;
        const size_t rb = ((size_t)e * FF + f) * FF + h * 16;
        const float xv = x[i * FF + ll];
        const float4* __restrict__ wp = (const float4*)(Wu + rb);
        const float4* __restrict__ cp = (const float4*)(Wcm + rb);
        float a0 = 0.f, a1 = 0.f;
#pragma unroll
        for (int q = 0; q < 4; ++q) {
            const float4 w4 = wp[q], c4 = cp[q];
            const int g0 = h * 16 + q * 4;
            DOT4(a0, w4, xv, g0)
            DOT4(a1, c4, xv, g0)
        }
        a0 += __shfl_xor(a0, 1);
        a1 += __shfl_xor(a1, 1);
        if (h == 0) {
            WUX[(size_t)e * FF + f] = a0;
            WCMX[(size_t)e * FF + f] = a1;
        }
        const float m_pair = sig_(a0 + bu_f) * tanhf(a1 + bcm_f);
        const float mv = __shfl(m_pair, 2 * ll);
        if (l < 32) {
            M1[(size_t)e * FF + ll] = mv;
            atomicAdd(&sin1[j * FF + ll], mv);
        }
        const float4* __restrict__ up = (const float4*)(Uu + rb);
        float aR = 0.f;
#pragma unroll
        for (int q = 0; q < 4; ++q) {
            const float4 u4 = up[q];
            const int g0 = h * 16 + q * 4;
            DOT4(aR, u4, mv, g0)
        }
        aR += __shfl_xor(aR, 1);
        const float rm_pair = sig_(a0 + aR + bu_f) * m_pair;
        const float rmv = __shfl(rm_pair, 2 * ll);
        if (l < 32) {
            RM[(size_t)e * FF + ll] = rmv;
            atomicAdd(&rout1[i * FF + ll], rmv);
        }
    }
}

// ---------------------------------------------------------------------------
// Steps 1..3. One wave per edge (grid-stride over compact list):
//   prev = sin_t[i] - M_in[j,i]
//   z = sig(WUX + Uu[e]@prev + bu)      (Uu row register-cached, reused for r')
//   rs = rout_t[i] - RM[e]; cm = tanh(WCMX + Ucm[e]@rs + bcm)
//   mnew = (1-z)*prev + z*cm -> M_out, sin_next[j] +=
//   r' = sig(WUX + Uu[e]@mnew + bu); RM[e] = r'*mnew; rout_next[i] +=
// ---------------------------------------------------------------------------
__global__ __launch_bounds__(256) void k_step(
        const int* __restrict__ elist, const int* __restrict__ meta,
        const float* __restrict__ Uu, const float* __restrict__ Ucm,
        const float* __restrict__ bu, const float* __restrict__ bcm,
        const float* __restrict__ WUX, const float* __restrict__ WCMX,
        const float* __restrict__ M_in, float* __restrict__ M_out,
        float* __restrict__ RM,
        const float* __restrict__ sin_t, const float* __restrict__ rout_t,
        float* __restrict__ sin_next, float* __restrict__ rout_next) {
    const int E = meta[0];
    const int gw = blockIdx.x * 4 + (threadIdx.x >> 6);
    const int l = threadIdx.x & 63;
    const int f = l >> 1, h = l & 1, ll = l & 31;
    const float bu_f = bu[f], bcm_f = bcm[f];
    for (int slot = gw; slot < E; slot += GSTRIDE) {
        const int e = elist[slot];
        const int i = e >> 7, j = e & 127;
        const size_t rb = ((size_t)e * FF + f) * FF + h * 16;

        const float prevv = sin_t[i * FF + ll] - M_in[((size_t)j * NN + i) * FF + ll];
        const float4* __restrict__ up = (const float4*)(Uu + rb);
        const float4 u0 = up[0], u1 = up[1], u2 = up[2], u3 = up[3];
        float aP = 0.f;
        {
            const int g0 = h * 16;
            DOT4(aP, u0, prevv, g0 + 0)
            DOT4(aP, u1, prevv, g0 + 4)
            DOT4(aP, u2, prevv, g0 + 8)
            DOT4(aP, u3, prevv, g0 + 12)
        }
        aP += __shfl_xor(aP, 1);
        const float wux_f = WUX[(size_t)e * FF + f];
        const float z = sig_(wux_f + aP + bu_f);

        const float rsv = rout_t[i * FF + ll] - RM[(size_t)e * FF + ll];
        const float4* __restrict__ cp = (const float4*)(Ucm + rb);
        float aC = 0.f;
        {
            const int g0 = h * 16;
            DOT4(aC, cp[0], rsv, g0 + 0)
            DOT4(aC, cp[1], rsv, g0 + 4)
            DOT4(aC, cp[2], rsv, g0 + 8)
            DOT4(aC, cp[3], rsv, g0 + 12)
        }
        aC += __shfl_xor(aC, 1);
        const float cmv = tanhf(WCMX[(size_t)e * FF + f] + aC + bcm_f);

        const float prev_f = __shfl(prevv, f);
        const float m_pair = (1.f - z) * prev_f + z * cmv;
        const float mv = __shfl(m_pair, 2 * ll);
        if (l < 32) {
            M_out[(size_t)e * FF + ll] = mv;
            atomicAdd(&sin_next[j * FF + ll], mv);
        }
        float aR = 0.f;
        {
            const int g0 = h * 16;
            DOT4(aR, u0, mv, g0 + 0)
            DOT4(aR, u1, mv, g0 + 4)
            DOT4(aR, u2, mv, g0 + 8)
            DOT4(aR, u3, mv, g0 + 12)
        }
        aR += __shfl_xor(aR, 1);
        const float rm_pair = sig_(wux_f + aR + bu_f) * m_pair;
        const float rmv = __shfl(rm_pair, 2 * ll);
        if (l < 32) {
            RM[(size_t)e * FF + ll] = rmv;
            atomicAdd(&rout_next[i * FF + ll], rmv);
        }
    }
}

// ---------------------------------------------------------------------------
// Step 4 + final encode, fused. Block = node i (1024 thr = 16 waves); edges
// of node i are contiguous in elist [meta[1+i], meta[2+i]). out_sum is
// block-local (LDS reduce) -> no atomics, no separate final dispatch.
// No r-lookahead needed in the last step.
// ---------------------------------------------------------------------------
__global__ __launch_bounds__(1024) void k_last(
        const int* __restrict__ elist, const int* __restrict__ meta,
        const float* __restrict__ x,
        const float* __restrict__ Uu, const float* __restrict__ Ucm,
        const float* __restrict__ bu, const float* __restrict__ bcm,
        const float* __restrict__ WUX, const float* __restrict__ WCMX,
        const float* __restrict__ M_in, const float* __restrict__ RM,
        const float* __restrict__ sin4, const float* __restrict__ rout4,
        const float* __restrict__ Unf, const float* __restrict__ Unm,
        float* __restrict__ out) {
    const int i = blockIdx.x;
    const int t = threadIdx.x;
    const int wv = t >> 6, l = t & 63;
    const int f = l >> 1, h = l & 1, ll = l & 31;
    const int rs = meta[1 + i], re = meta[2 + i];
    const float sinv = sin4[i * FF + ll];
    const float routv = rout4[i * FF + ll];
    const float bu_f = bu[f], bcm_f = bcm[f];

    float osv = 0.f;
    for (int s = rs + wv; s < re; s += 16) {
        const int e = elist[s];
        const int j = e & 127;
        const size_t rb = ((size_t)e * FF + f) * FF + h * 16;
        const float prevv = sinv - M_in[((size_t)j * NN + i) * FF + ll];
        const float4* __restrict__ up = (const float4*)(Uu + rb);
        float aP = 0.f;
        {
            const int g0 = h * 16;
            DOT4(aP, up[0], prevv, g0 + 0)
            DOT4(aP, up[1], prevv, g0 + 4)
            DOT4(aP, up[2], prevv, g0 + 8)
            DOT4(aP, up[3], prevv, g0 + 12)
        }
        aP += __shfl_xor(aP, 1);
        const float z = sig_(WUX[(size_t)e * FF + f] + aP + bu_f);

        const float rsv = routv - RM[(size_t)e * FF + ll];
        const float4* __restrict__ cp = (const float4*)(Ucm + rb);
        float aC = 0.f;
        {
            const int g0 = h * 16;
            DOT4(aC, cp[0], rsv, g0 + 0)
            DOT4(aC, cp[1], rsv, g0 + 4)
            DOT4(aC, cp[2], rsv, g0 + 8)
            DOT4(aC, cp[3], rsv, g0 + 12)
        }
        aC += __shfl_xor(aC, 1);
        const float cmv = tanhf(WCMX[(size_t)e * FF + f] + aC + bcm_f);

        const float prev_f = __shfl(prevv, f);
        const float m_pair = (1.f - z) * prev_f + z * cmv;
        osv += __shfl(m_pair, 2 * ll);        // vector layout accumulate
    }
    __shared__ float opp[16][FF];
    if (l < 32) opp[wv][ll] = osv;
    __syncthreads();
    if (t < 64) {
        float os = 0.f;
#pragma unroll
        for (int g = 0; g < 16; ++g) os += opp[g][ll];
        const float xv = x[i * FF + ll];
        const size_t rb = ((size_t)i * FF + f) * FF + h * 16;
        const float4* __restrict__ fp = (const float4*)(Unf + rb);
        const float4* __restrict__ mp = (const float4*)(Unm + rb);
        float a = 0.f;
#pragma unroll
        for (int q = 0; q < 4; ++q) {
            const float4 f4 = fp[q], m4 = mp[q];
            const int g0 = h * 16 + q * 4;
            DOT4(a, f4, xv, g0)
            DOT4(a, m4, os, g0)
        }
        a += __shfl_xor(a, 1);
        if (h == 0) out[i * FF + f] = fmaxf(a, 0.f);
    }
}

extern "C" void kernel_launch(void* const* d_in, const int* in_sizes, int n_in,
                              void* d_out, int out_size, void* d_ws, size_t ws_size,
                              hipStream_t stream) {
    const float* x   = (const float*)d_in[0];
    const int*   adj = (const int*)d_in[1];
    const float* Wu  = (const float*)d_in[2];
    const float* Uu  = (const float*)d_in[3];
    const float* Wcm = (const float*)d_in[4];
    const float* Ucm = (const float*)d_in[5];
    const float* bu  = (const float*)d_in[6];
    const float* bcm = (const float*)d_in[7];
    const float* Unf = (const float*)d_in[8];
    const float* Unm = (const float*)d_in[9];
    float* out = (float*)d_out;

    const size_t EF = (size_t)NN * NN * FF;  // 524288 floats per dense [N,N,F]
    const size_t NF = (size_t)NN * FF;       // 4096
    float* p    = (float*)d_ws;
    float* MA   = p; p += EF;
    float* MB   = p; p += EF;
    float* WUX  = p; p += EF;
    float* WCMX = p; p += EF;
    float* RM   = p; p += EF;
    float* acc  = p; p += 8 * NF;            // sin1..4, rout1..4 (contiguous)
    int* elist  = (int*)p;
    int* meta   = elist + NN * NN;           // meta[0]=E, meta[1..129]=row_start
    float* sinb[4]  = {acc, acc + NF, acc + 2 * NF, acc + 3 * NF};
    float* routb[4] = {acc + 4 * NF, acc + 5 * NF, acc + 6 * NF, acc + 7 * NF};
    // ws use: ~10.2 MiB

    k_prep<<<1, 1024, 0, stream>>>(adj, acc, elist, meta);
    k_step0<<<NBLK_E, 256, 0, stream>>>(elist, meta, x, Wu, Wcm, Uu, bu, bcm,
                                        WUX, WCMX, MA, RM, sinb[0], routb[0]);
    // t=1: MA->MB ; t=2: MB->MA ; t=3: MA->MB ; t=4 (k_last): reads MB
    k_step<<<NBLK_E, 256, 0, stream>>>(elist, meta, Uu, Ucm, bu, bcm, WUX, WCMX,
                                       MA, MB, RM, sinb[0], routb[0],
                                       sinb[1], routb[1]);
    k_step<<<NBLK_E, 256, 0, stream>>>(elist, meta, Uu, Ucm, bu, bcm, WUX, WCMX,
                                       MB, MA, RM, sinb[1], routb[1],
                                       sinb[2], routb[2]);
    k_step<<<NBLK_E, 256, 0, stream>>>(elist, meta, Uu, Ucm, bu, bcm, WUX, WCMX,
                                       MA, MB, RM, sinb[2], routb[2],
                                       sinb[3], routb[3]);
    k_last<<<NN, 1024, 0, stream>>>(elist, meta, x, Uu, Ucm, bu, bcm,
                                    WUX, WCMX, MB, RM, sinb[3], routb[3],
                                    Unf, Unm, out);
}